// Round 4
// baseline (188.801 us; speedup 1.0000x reference)
//
#include <hip/hip_runtime.h>

// PairwiseRankLoss: U=262144 users x G=64 items, K=2, MARGIN=0.3
// One 64-lane wave per user.
//  - pos mask via per-lane RANK: rank_l = #{m: yt_m < yt_l}, pos = rank>=32
//    (equivalent to yt > median for distinct values). Rank computed as
//    64 x (v_cmp_lt + v_addc) against SGPR pivots s_loaded from the row:
//    2 VALU ops/pivot, zero SALU, zero DS.
//  - top-2 rand per side via DPP max-reduce + 1-op ballot + readlane
//    (tie-break = lowest index, matching lax.top_k).
// Deterministic two-stage reduction via d_ws.

static constexpr int kUsers = 262144;
static constexpr int kBlock = 256;                  // 4 waves / block
static constexpr int kGrid  = 2048;                 // 8 blocks / CU
static constexpr int kWavesPerBlock = kBlock / 64;
static constexpr int kTotalWaves = kGrid * kWavesPerBlock;  // 8192
static constexpr int kUsersPerWave = kUsers / kTotalWaves;  // 32
static constexpr float kMargin = 0.3f;

typedef float f32x16 __attribute__((ext_vector_type(16)));

template<int CTRL>
static __device__ __forceinline__ float dpp_mov(float x) {
    return __int_as_float(__builtin_amdgcn_update_dpp(
        __float_as_int(x), __float_as_int(x), CTRL, 0xF, 0xF, false));
}

// max across 64 lanes; valid in lane 63. VALU-only, no DS.
static __device__ __forceinline__ float wavemax63(float x) {
    x = fmaxf(x, dpp_mov<0xB1>(x));    // quad_perm xor1
    x = fmaxf(x, dpp_mov<0x4E>(x));    // quad_perm xor2
    x = fmaxf(x, dpp_mov<0x141>(x));   // row_half_mirror = xor7
    x = fmaxf(x, dpp_mov<0x128>(x));   // row_ror:8
    x = fmaxf(x, dpp_mov<0x142>(x));   // row_bcast15
    x = fmaxf(x, dpp_mov<0x143>(x));   // row_bcast31
    return x;
}

static __device__ __forceinline__ float readlane_f(float x, int l) {
    return __uint_as_float(__builtin_amdgcn_readlane(__float_as_uint(x), l));
}

// 64 consecutive floats at wave-uniform address -> SGPRs (scalar-mem pipe)
static __device__ __forceinline__ void sload64(const float* p, f32x16& a,
                                               f32x16& b, f32x16& c, f32x16& d) {
    asm volatile(
        "s_load_dwordx16 %0, %4, 0x0\n\t"
        "s_load_dwordx16 %1, %4, 0x40\n\t"
        "s_load_dwordx16 %2, %4, 0x80\n\t"
        "s_load_dwordx16 %3, %4, 0xC0\n\t"
        "s_waitcnt lgkmcnt(0)"
        : "=&s"(a), "=&s"(b), "=&s"(c), "=&s"(d)
        : "s"(p)
        : "memory");
}

// rank += (pivot < yt); exactly 2 VALU ops, explicit carry pair (no vcc).
static __device__ __forceinline__ void rank_step(unsigned& rank, float yt, float pivot) {
    unsigned long long cc;
    asm("v_cmp_lt_f32 %1, %3, %2\n\t"
        "v_addc_co_u32 %0, %1, 0, %0, %1"
        : "+v"(rank), "=&s"(cc)
        : "v"(yt), "s"(pivot));
}

__global__ __launch_bounds__(kBlock, 8)
void prl_user_kernel(const float* __restrict__ y_hat,
                     const float* __restrict__ y_true,
                     const float* __restrict__ rnd,
                     float* __restrict__ partials)
{
    const int lane = threadIdx.x & 63;
    const int wid  = (blockIdx.x * kBlock + threadIdx.x) >> 6;

    float acc = 0.0f;

    #pragma unroll 1
    for (int it = 0; it < kUsersPerWave; ++it) {
        const int u     = wid * kUsersPerWave + it;
        const int ubase = __builtin_amdgcn_readfirstlane(u << 6);

        // pivots for the whole row into SGPRs (scalar pipe, 4 instrs)
        f32x16 sa, sb, sc, sd;
        sload64(y_true + ubase, sa, sb, sc, sd);

        const float yh = y_hat[ubase + lane];
        const float yt = y_true[ubase + lane];
        const float r  = rnd[ubase + lane];

        // ---- rank_l = #{m: yt_m < yt_l}; pos = rank >= 32 ----
        unsigned rank = 0;
        #pragma unroll
        for (int h = 0; h < 16; ++h) rank_step(rank, yt, sa[h]);
        #pragma unroll
        for (int h = 0; h < 16; ++h) rank_step(rank, yt, sb[h]);
        #pragma unroll
        for (int h = 0; h < 16; ++h) rank_step(rank, yt, sc[h]);
        #pragma unroll
        for (int h = 0; h < 16; ++h) rank_step(rank, yt, sd[h]);
        const bool pos = (rank >= 32u);

        // ---- top-2 rand per side via DPP max + ballot; gather via readlane --
        float P0, P1, N0, N1;
        #pragma unroll
        for (int side = 0; side < 2; ++side) {
            const bool m = (side == 0) ? pos : !pos;
            float key = m ? r : -2.0f;          // r in [0,1): -2 acts as -inf
            const float smx = readlane_f(wavemax63(key), 63);
            const int w1 = __builtin_ctzll(__ballot(key == smx));  // low-idx tie
            const float A0 = readlane_f(yh, w1);
            key = (lane == w1) ? -3.0f : key;   // exclude winner
            const float smx2 = readlane_f(wavemax63(key), 63);
            const int w2 = __builtin_ctzll(__ballot(key == smx2));
            const float A1 = readlane_f(yh, w2);
            if (side == 0) { P0 = A0; P1 = A1; }
            else           { N0 = A0; N1 = A1; }
        }

        // ---- 2x2 hinge mean ----
        float s = 0.0f;
        s += fmaxf(kMargin - (P0 - N0), 0.0f);
        s += fmaxf(kMargin - (P0 - N1), 0.0f);
        s += fmaxf(kMargin - (P1 - N0), 0.0f);
        s += fmaxf(kMargin - (P1 - N1), 0.0f);
        acc += 0.25f * s;
    }

    // block partial (acc is wave-uniform; take lane 0 of each wave)
    __shared__ float wsum[kWavesPerBlock];
    if (lane == 0) wsum[threadIdx.x >> 6] = acc;
    __syncthreads();
    if (threadIdx.x == 0) {
        float t = 0.0f;
        #pragma unroll
        for (int i = 0; i < kWavesPerBlock; ++i) t += wsum[i];
        partials[blockIdx.x] = t;
    }
}

__global__ void prl_reduce_kernel(const float* __restrict__ partials,
                                  float* __restrict__ out)
{
    // one block of 256 threads reduces kGrid partials in a fixed order
    float t = 0.0f;
    for (int i = threadIdx.x; i < kGrid; i += 256) t += partials[i];
    #pragma unroll
    for (int s = 32; s > 0; s >>= 1) t += __shfl_xor(t, s);
    __shared__ float ws[4];
    if ((threadIdx.x & 63) == 0) ws[threadIdx.x >> 6] = t;
    __syncthreads();
    if (threadIdx.x == 0) {
        out[0] = (ws[0] + ws[1] + ws[2] + ws[3]) * (1.0f / (float)kUsers);
    }
}

extern "C" void kernel_launch(void* const* d_in, const int* in_sizes, int n_in,
                              void* d_out, int out_size, void* d_ws, size_t ws_size,
                              hipStream_t stream) {
    const float* y_hat  = (const float*)d_in[0];
    const float* y_true = (const float*)d_in[1];
    const float* rnd    = (const float*)d_in[2];
    // d_in[3] = user_idx: contiguous equal-size segments -> never read
    float* partials = (float*)d_ws;          // kGrid floats = 8 KiB scratch
    float* out      = (float*)d_out;

    hipLaunchKernelGGL(prl_user_kernel, dim3(kGrid), dim3(kBlock), 0, stream,
                       y_hat, y_true, rnd, partials);
    hipLaunchKernelGGL(prl_reduce_kernel, dim3(1), dim3(256), 0, stream,
                       partials, out);
}

// Round 5
// 128.239 us; speedup vs baseline: 1.4723x; 1.4723x over previous
//
#include <hip/hip_runtime.h>

// PairwiseRankLoss: U=262144 users x G=64 items, K=2, MARGIN=0.3
// One 64-lane wave per user. ALL cross-lane ops on the per-SIMD VALU:
//   - DPP quad_perm/row_ror for xor1/2/8, 3-mov DPP composition for xor4,
//     gfx950 v_permlane16/32_swap for the 16/32 crossings. Zero DS ops,
//     zero scalar-mem, zero SALU chains (the per-CU-shared DS pipe was the
//     R1/R2 bottleneck; SALU/K$ were the R3/R4 regressions).
//   - median mask via truncated bitonic: sort 32-blocks (15 CE stages),
//     one k=64 split stage, then a31 = max(lower half); pos = yt > a31
//     (exactly equal to yt > median for adjacent order stats, ties incl.)
//   - top-2 rand per side via all-lane DPP max-fold + ballot + readlane
//     (tie-break = lowest index, matching lax.top_k).
// Deterministic two-stage reduction via d_ws.

static constexpr int kUsers = 262144;
static constexpr int kBlock = 256;                  // 4 waves / block
static constexpr int kGrid  = 2048;                 // 8 blocks / CU
static constexpr int kWavesPerBlock = kBlock / 64;
static constexpr int kTotalWaves = kGrid * kWavesPerBlock;  // 8192
static constexpr int kUsersPerWave = kUsers / kTotalWaves;  // 32
static constexpr float kMargin = 0.3f;

typedef unsigned uint2v __attribute__((ext_vector_type(2)));

template<int CTRL>
static __device__ __forceinline__ float dppf(float x) {
    return __uint_as_float((unsigned)__builtin_amdgcn_update_dpp(
        (int)__float_as_uint(x), (int)__float_as_uint(x), CTRL, 0xF, 0xF, false));
}

// gfx950 VALU cross-row swaps. After swap16(a=x,b=x):
//   a = rows [r0,r0,r2,r2], b = rows [r1,r1,r3,r3]  (row = 16 lanes)
// After swap32(a=x,b=x): a = [lo32,lo32], b = [hi32,hi32].
static __device__ __forceinline__ void swap16(float& a, float& b) {
    uint2v t = __builtin_amdgcn_permlane16_swap(__float_as_uint(a),
                                                __float_as_uint(b), false, false);
    a = __uint_as_float(t[0]); b = __uint_as_float(t[1]);
}
static __device__ __forceinline__ void swap32(float& a, float& b) {
    uint2v t = __builtin_amdgcn_permlane32_swap(__float_as_uint(a),
                                                __float_as_uint(b), false, false);
    a = __uint_as_float(t[0]); b = __uint_as_float(t[1]);
}

static __device__ __forceinline__ float readlane_f(float x, int l) {
    return __uint_as_float(__builtin_amdgcn_readlane(__float_as_uint(x), l));
}

// partner values x[lane ^ j], VALU-only
static __device__ __forceinline__ float px1(float x){ return dppf<0xB1>(x); }   // quad_perm xor1
static __device__ __forceinline__ float px2(float x){ return dppf<0x4E>(x); }   // quad_perm xor2
static __device__ __forceinline__ float px4(float x){                            // xor1^xor2^xor7 = xor4
    return dppf<0x141>(dppf<0x4E>(dppf<0xB1>(x)));
}
static __device__ __forceinline__ float px8(float x){ return dppf<0x128>(x); }  // row_ror:8 = xor8

// all-lane max over 64 lanes, VALU-only; result uniform in every lane
static __device__ __forceinline__ float fold64max(float x) {
    x = fmaxf(x, dppf<0x128>(x));   // row_ror:8
    x = fmaxf(x, dppf<0x124>(x));   // row_ror:4
    x = fmaxf(x, dppf<0x122>(x));   // row_ror:2
    x = fmaxf(x, dppf<0x121>(x));   // row_ror:1  -> max within each 16-row
    { float a = x, b = x; swap16(a, b); x = fmaxf(a, b); }  // -> within 32
    { float a = x, b = x; swap32(a, b); x = fmaxf(a, b); }  // -> within 64
    return x;
}

__global__ __launch_bounds__(kBlock, 8)
void prl_user_kernel(const float* __restrict__ y_hat,
                     const float* __restrict__ y_true,
                     const float* __restrict__ rnd,
                     float* __restrict__ partials)
{
    const int lane = threadIdx.x & 63;
    const int wid  = (blockIdx.x * kBlock + threadIdx.x) >> 6;

    // keepmin predicates, loop-invariant (lane-mask sgpr pairs after LICM)
    const bool km_2_1   = ((lane & 2) == 0) == ((lane & 1) == 0);
    const bool km_4_2   = ((lane & 4) == 0) == ((lane & 2) == 0);
    const bool km_4_1   = ((lane & 4) == 0) == ((lane & 1) == 0);
    const bool km_8_4   = ((lane & 8) == 0) == ((lane & 4) == 0);
    const bool km_8_2   = ((lane & 8) == 0) == ((lane & 2) == 0);
    const bool km_8_1   = ((lane & 8) == 0) == ((lane & 1) == 0);
    const bool km_16_8  = ((lane & 16) == 0) == ((lane & 8) == 0);
    const bool km_16_4  = ((lane & 16) == 0) == ((lane & 4) == 0);
    const bool km_16_2  = ((lane & 16) == 0) == ((lane & 2) == 0);
    const bool km_16_1  = ((lane & 16) == 0) == ((lane & 1) == 0);
    const bool km_32_16 = ((lane & 32) == 0) == ((lane & 16) == 0);
    const bool km_32_8  = ((lane & 32) == 0) == ((lane & 8) == 0);
    const bool km_32_4  = ((lane & 32) == 0) == ((lane & 4) == 0);
    const bool km_32_2  = ((lane & 32) == 0) == ((lane & 2) == 0);
    const bool km_32_1  = ((lane & 32) == 0) == ((lane & 1) == 0);
    const bool lo32     = (lane & 32) == 0;

    float acc = 0.0f;

    #pragma unroll 1
    for (int it = 0; it < kUsersPerWave; ++it) {
        const int base = ((wid * kUsersPerWave + it) << 6) + lane;
        const float yh = y_hat[base];
        const float yt = y_true[base];
        const float r  = rnd[base];

        // ---- truncated bitonic on yt: sort 32-blocks, then split ----
        float x = yt;
        auto CE = [&](float p, bool kmn) {
            const float mn = fminf(x, p), mx = fmaxf(x, p);
            x = kmn ? mn : mx;
        };
        CE(px1(x), km_2_1);
        CE(px2(x), km_4_2);  CE(px1(x), km_4_1);
        CE(px4(x), km_8_4);  CE(px2(x), km_8_2);  CE(px1(x), km_8_1);
        CE(px8(x), km_16_8); CE(px4(x), km_16_4); CE(px2(x), km_16_2); CE(px1(x), km_16_1);
        { float a = x, b = x; swap16(a, b);
          const float mn = fminf(a, b), mx = fmaxf(a, b); x = km_32_16 ? mn : mx; }
        CE(px8(x), km_32_8); CE(px4(x), km_32_4); CE(px2(x), km_32_2); CE(px1(x), km_32_1);
        // k=64 split stage: lower 32 lanes <- elementwise min = 32 smallest
        { float a = x, b = x; swap32(a, b);
          const float mn = fminf(a, b), mx = fmaxf(a, b); x = lo32 ? mn : mx; }

        // a31 = max of lower half (fold within 32-groups; read lane 0)
        float y = x;
        y = fmaxf(y, dppf<0x128>(y));
        y = fmaxf(y, dppf<0x124>(y));
        y = fmaxf(y, dppf<0x122>(y));
        y = fmaxf(y, dppf<0x121>(y));
        { float a = y, b = y; swap16(a, b); y = fmaxf(a, b); }
        const float a31 = readlane_f(y, 0);
        const bool  pos = yt > a31;          // == (yt > median), bit-exact

        // ---- top-2 rand per side; gather y_hat of winners ----
        float P0, P1, N0, N1;
        {
            const float key = pos ? r : -2.0f;        // r in [0,1)
            const float m1  = fold64max(key);
            const int   w1  = (int)__builtin_ctzll(__ballot(key == m1));
            P0 = readlane_f(yh, w1);
            const float key2 = (lane == w1) ? -4.0f : key;
            const float m2   = fold64max(key2);
            const int   w2   = (int)__builtin_ctzll(__ballot(key2 == m2));
            P1 = readlane_f(yh, w2);
        }
        {
            const float key = pos ? -2.0f : r;
            const float m1  = fold64max(key);
            const int   w1  = (int)__builtin_ctzll(__ballot(key == m1));
            N0 = readlane_f(yh, w1);
            const float key2 = (lane == w1) ? -4.0f : key;
            const float m2   = fold64max(key2);
            const int   w2   = (int)__builtin_ctzll(__ballot(key2 == m2));
            N1 = readlane_f(yh, w2);
        }

        // ---- 2x2 hinge mean ----
        float s = 0.0f;
        s += fmaxf(kMargin - (P0 - N0), 0.0f);
        s += fmaxf(kMargin - (P0 - N1), 0.0f);
        s += fmaxf(kMargin - (P1 - N0), 0.0f);
        s += fmaxf(kMargin - (P1 - N1), 0.0f);
        acc += 0.25f * s;
    }

    // block partial (acc is wave-uniform; take lane 0 of each wave)
    __shared__ float wsum[kWavesPerBlock];
    if (lane == 0) wsum[threadIdx.x >> 6] = acc;
    __syncthreads();
    if (threadIdx.x == 0) {
        float t = 0.0f;
        #pragma unroll
        for (int i = 0; i < kWavesPerBlock; ++i) t += wsum[i];
        partials[blockIdx.x] = t;
    }
}

__global__ void prl_reduce_kernel(const float* __restrict__ partials,
                                  float* __restrict__ out)
{
    // one block of 256 threads reduces kGrid partials in a fixed order
    float t = 0.0f;
    for (int i = threadIdx.x; i < kGrid; i += 256) t += partials[i];
    #pragma unroll
    for (int s = 32; s > 0; s >>= 1) t += __shfl_xor(t, s);
    __shared__ float ws[4];
    if ((threadIdx.x & 63) == 0) ws[threadIdx.x >> 6] = t;
    __syncthreads();
    if (threadIdx.x == 0) {
        out[0] = (ws[0] + ws[1] + ws[2] + ws[3]) * (1.0f / (float)kUsers);
    }
}

extern "C" void kernel_launch(void* const* d_in, const int* in_sizes, int n_in,
                              void* d_out, int out_size, void* d_ws, size_t ws_size,
                              hipStream_t stream) {
    const float* y_hat  = (const float*)d_in[0];
    const float* y_true = (const float*)d_in[1];
    const float* rnd    = (const float*)d_in[2];
    // d_in[3] = user_idx: contiguous equal-size segments -> never read
    float* partials = (float*)d_ws;          // kGrid floats = 8 KiB scratch
    float* out      = (float*)d_out;

    hipLaunchKernelGGL(prl_user_kernel, dim3(kGrid), dim3(kBlock), 0, stream,
                       y_hat, y_true, rnd, partials);
    hipLaunchKernelGGL(prl_reduce_kernel, dim3(1), dim3(256), 0, stream,
                       partials, out);
}

// Round 6
// 50.187 us; speedup vs baseline: 3.7620x; 2.5552x over previous
//
#include <hip/hip_runtime.h>

// PairwiseRankLoss: U=262144 users x G=64 items, K=2, MARGIN=0.3
// 4 users per wave: 16 lanes/user, 4 items/lane (float4), item i = 4t+s.
// Cross-lane op COUNT minimized (R5 lesson: cross-lane ops are the cost):
//   - bitonic j=1,2 exchanges are in-lane register min/max (free-rate)
//   - j=4,8 via quad_perm DPP; j=16 via ds_swizzle xor4; split via
//     ds_swizzle xor15 mirror; folds via row_ror DPP (16-lane groups)
//   - every cross-lane instruction serves 4 users simultaneously
// Median: sort both 32-halves ascending, bitonic split vs mirrored half,
// a31 = max(lower 32) -> pos = yt > a31 (== yt > median, ties incl.)
// Top-2 rand/side: in-lane (m1,m2) + ror-fold on exact u32 r-bits; locate
// via ballot+ffbl (lowest flat index on ties = lax.top_k); gather via
// one ds_bpermute per winner. Deterministic two-stage reduction via d_ws.

static constexpr int kUsers = 262144;
static constexpr int kBlock = 256;                  // 4 waves / block
static constexpr int kGrid  = 2048;
static constexpr int kWavesPerBlock = kBlock / 64;
static constexpr int kTotalWaves = kGrid * kWavesPerBlock;   // 8192
static constexpr int kUsersPerWave = kUsers / kTotalWaves;   // 32
static constexpr int kUsersPerIter = 4;
static constexpr int kIters = kUsersPerWave / kUsersPerIter; // 8
static constexpr float kMargin = 0.3f;

template<int CTRL>
static __device__ __forceinline__ float dppf(float x) {
    return __uint_as_float((unsigned)__builtin_amdgcn_update_dpp(
        (int)__float_as_uint(x), (int)__float_as_uint(x), CTRL, 0xF, 0xF, false));
}
template<int CTRL>
static __device__ __forceinline__ unsigned dppu(unsigned x) {
    return (unsigned)__builtin_amdgcn_update_dpp((int)x, (int)x, CTRL, 0xF, 0xF, false);
}
template<int PAT>
static __device__ __forceinline__ float swzf(float x) {
    return __uint_as_float((unsigned)__builtin_amdgcn_ds_swizzle(
        (int)__float_as_uint(x), PAT));
}
static __device__ __forceinline__ unsigned umax_(unsigned a, unsigned b){ return a>b?a:b; }
static __device__ __forceinline__ unsigned umin_(unsigned a, unsigned b){ return a<b?a:b; }

// in-lane compare-exchange: a <- min, b <- max if asc, else swapped
#define CE2(a, b, asc) { float mn_=fminf(a,b), mx_=fmaxf(a,b); \
                         (a)=(asc)?mn_:mx_; (b)=(asc)?mx_:mn_; }
// in-lane CE with compile-time ascending
#define CE2A(a, b)     { float mn_=fminf(a,b), mx_=fmaxf(a,b); (a)=mn_; (b)=mx_; }
#define CE2D(a, b)     { float mn_=fminf(a,b), mx_=fmaxf(a,b); (a)=mx_; (b)=mn_; }
// cross-lane CE on one slot register: keep min if km else max
#define CEX(w, p, km)  { (w) = (km) ? fminf(w,p) : fmaxf(w,p); }

__global__ __launch_bounds__(kBlock, 8)
void prl_user_kernel(const float* __restrict__ y_hat,
                     const float* __restrict__ y_true,
                     const float* __restrict__ rnd,
                     float* __restrict__ partials)
{
    const int lane = threadIdx.x & 63;
    const int wid  = (blockIdx.x * kBlock + threadIdx.x) >> 6;
    const int t    = lane & 15;          // lane within user group
    const int g    = lane >> 4;          // user group (0..3) within wave
    const int tt   = t & 7;              // lane within 32-item sort half

    // loop-invariant keepmin predicates (hoisted to sgpr lane-masks)
    const bool asc4  = (tt & 1) == 0;
    const bool asc8  = (tt & 2) == 0;
    const bool asc16 = (tt & 4) == 0;
    const bool km84  = ((tt & 2) == 0) == ((tt & 1) == 0);
    const bool km168 = ((tt & 4) == 0) == ((tt & 2) == 0);
    const bool km164 = ((tt & 4) == 0) == ((tt & 1) == 0);

    float acc = 0.0f;

    #pragma unroll 1
    for (int it = 0; it < kIters; ++it) {
        const int u0  = wid * kUsersPerWave + it * kUsersPerIter;
        const int idx = (u0 << 6) + (lane << 2);   // wave reads 1KB contiguous
        const float4 vh = *reinterpret_cast<const float4*>(y_hat + idx);
        const float4 vt = *reinterpret_cast<const float4*>(y_true + idx);
        const float4 vr = *reinterpret_cast<const float4*>(rnd  + idx);

        // ---- sort both 32-halves ascending (local pos q = 4*tt + s) ----
        float w0 = vt.x, w1 = vt.y, w2 = vt.z, w3 = vt.w;
        // (k=2, j=1): compile-time dirs
        CE2A(w0, w1); CE2D(w2, w3);
        // (4,2) then (4,1)
        CE2(w0, w2, asc4); CE2(w1, w3, asc4);
        CE2(w0, w1, asc4); CE2(w2, w3, asc4);
        // (8,4): cross lane^1
        { float p0=dppf<0xB1>(w0), p1=dppf<0xB1>(w1), p2=dppf<0xB1>(w2), p3=dppf<0xB1>(w3);
          CEX(w0,p0,km84); CEX(w1,p1,km84); CEX(w2,p2,km84); CEX(w3,p3,km84); }
        // (8,2), (8,1)
        CE2(w0, w2, asc8); CE2(w1, w3, asc8);
        CE2(w0, w1, asc8); CE2(w2, w3, asc8);
        // (16,8): cross lane^2
        { float p0=dppf<0x4E>(w0), p1=dppf<0x4E>(w1), p2=dppf<0x4E>(w2), p3=dppf<0x4E>(w3);
          CEX(w0,p0,km168); CEX(w1,p1,km168); CEX(w2,p2,km168); CEX(w3,p3,km168); }
        // (16,4): cross lane^1
        { float p0=dppf<0xB1>(w0), p1=dppf<0xB1>(w1), p2=dppf<0xB1>(w2), p3=dppf<0xB1>(w3);
          CEX(w0,p0,km164); CEX(w1,p1,km164); CEX(w2,p2,km164); CEX(w3,p3,km164); }
        // (16,2), (16,1)
        CE2(w0, w2, asc16); CE2(w1, w3, asc16);
        CE2(w0, w1, asc16); CE2(w2, w3, asc16);
        // (32,16): cross lane^4 via ds_swizzle xor4
        { float p0=swzf<0x101F>(w0), p1=swzf<0x101F>(w1),
                p2=swzf<0x101F>(w2), p3=swzf<0x101F>(w3);
          CEX(w0,p0,asc16); CEX(w1,p1,asc16); CEX(w2,p2,asc16); CEX(w3,p3,asc16); }
        // (32,8): cross lane^2
        { float p0=dppf<0x4E>(w0), p1=dppf<0x4E>(w1), p2=dppf<0x4E>(w2), p3=dppf<0x4E>(w3);
          CEX(w0,p0,asc8); CEX(w1,p1,asc8); CEX(w2,p2,asc8); CEX(w3,p3,asc8); }
        // (32,4): cross lane^1
        { float p0=dppf<0xB1>(w0), p1=dppf<0xB1>(w1), p2=dppf<0xB1>(w2), p3=dppf<0xB1>(w3);
          CEX(w0,p0,asc4); CEX(w1,p1,asc4); CEX(w2,p2,asc4); CEX(w3,p3,asc4); }
        // (32,2), (32,1): ascending everywhere
        CE2A(w0, w2); CE2A(w1, w3);
        CE2A(w0, w1); CE2A(w2, w3);

        // ---- split vs mirrored other half: lower-32 multiset ----
        // partner of (lane t, slot s) is (t^15, 3-s)
        const float l0 = fminf(w0, swzf<0x3C1F>(w3));
        const float l1 = fminf(w1, swzf<0x3C1F>(w2));
        const float l2 = fminf(w2, swzf<0x3C1F>(w1));
        const float l3 = fminf(w3, swzf<0x3C1F>(w0));

        // a31 = max of lower 32 (group-uniform after ror fold)
        float m = fmaxf(fmaxf(l0, l1), fmaxf(l2, l3));
        m = fmaxf(m, dppf<0x128>(m));
        m = fmaxf(m, dppf<0x124>(m));
        m = fmaxf(m, dppf<0x122>(m));
        m = fmaxf(m, dppf<0x121>(m));
        const float a31 = m;

        const bool p0m = vt.x > a31, p1m = vt.y > a31,
                   p2m = vt.z > a31, p3m = vt.w > a31;
        const unsigned rb0 = __float_as_uint(vr.x), rb1 = __float_as_uint(vr.y),
                       rb2 = __float_as_uint(vr.z), rb3 = __float_as_uint(vr.w);

        float P0, P1, N0, N1;
        #pragma unroll
        for (int side = 0; side < 2; ++side) {
            const unsigned k0 = ((side == 0) ? p0m : !p0m) ? rb0 : 0u;
            const unsigned k1 = ((side == 0) ? p1m : !p1m) ? rb1 : 0u;
            const unsigned k2 = ((side == 0) ? p2m : !p2m) ? rb2 : 0u;
            const unsigned k3 = ((side == 0) ? p3m : !p3m) ? rb3 : 0u;
            // in-lane top-2 of 4
            const unsigned a1 = umax_(k0,k1), a2 = umin_(k0,k1);
            const unsigned b1 = umax_(k2,k3), b2 = umin_(k2,k3);
            unsigned m1 = umax_(a1,b1);
            unsigned m2 = umax_(umin_(a1,b1), umax_(a2,b2));
            // ror-fold (m1,m2) across 16 lanes; group-uniform result
            { unsigned q1=dppu<0x128>(m1), q2=dppu<0x128>(m2);
              unsigned n2=umax_(umin_(m1,q1), umax_(m2,q2)); m1=umax_(m1,q1); m2=n2; }
            { unsigned q1=dppu<0x124>(m1), q2=dppu<0x124>(m2);
              unsigned n2=umax_(umin_(m1,q1), umax_(m2,q2)); m1=umax_(m1,q1); m2=n2; }
            { unsigned q1=dppu<0x122>(m1), q2=dppu<0x122>(m2);
              unsigned n2=umax_(umin_(m1,q1), umax_(m2,q2)); m1=umax_(m1,q1); m2=n2; }
            { unsigned q1=dppu<0x121>(m1), q2=dppu<0x121>(m2);
              unsigned n2=umax_(umin_(m1,q1), umax_(m2,q2)); m1=umax_(m1,q1); m2=n2; }

            // locate (lowest flat index) + gather y_hat for V in {m1, m2}
            float A[2];
            const unsigned vv[2] = { m1, m2 };
            #pragma unroll
            for (int j = 0; j < 2; ++j) {
                const unsigned V = vv[j];
                const bool c0 = (k0 == V), c1 = (k1 == V),
                           c2 = (k2 == V), c3 = (k3 == V);
                const float val = c0 ? vh.x : (c1 ? vh.y : (c2 ? vh.z : vh.w));
                const unsigned long long bal = __ballot(c0 | c1 | c2 | c3);
                const unsigned fld = (unsigned)(bal >> (g << 4)) & 0xFFFFu;
                const int tw = __builtin_ctz(fld);
                A[j] = __shfl(val, (lane & 48) | tw);
            }
            if (side == 0) { P0 = A[0]; P1 = A[1]; }
            else           { N0 = A[0]; N1 = A[1]; }
        }

        // ---- 2x2 hinge mean ----
        float s = 0.0f;
        s += fmaxf(kMargin - (P0 - N0), 0.0f);
        s += fmaxf(kMargin - (P0 - N1), 0.0f);
        s += fmaxf(kMargin - (P1 - N0), 0.0f);
        s += fmaxf(kMargin - (P1 - N1), 0.0f);
        acc = fmaf(0.25f, s, acc);
    }

    // acc is uniform within each 16-lane group; sum the 4 group leaders
    float contrib = (t == 0) ? acc : 0.0f;
    contrib += __shfl_xor(contrib, 32);
    contrib += __shfl_xor(contrib, 16);

    __shared__ float wsum[kWavesPerBlock];
    if (lane == 0) wsum[threadIdx.x >> 6] = contrib;
    __syncthreads();
    if (threadIdx.x == 0) {
        float tsum = 0.0f;
        #pragma unroll
        for (int i = 0; i < kWavesPerBlock; ++i) tsum += wsum[i];
        partials[blockIdx.x] = tsum;
    }
}

__global__ void prl_reduce_kernel(const float* __restrict__ partials,
                                  float* __restrict__ out)
{
    float tv = 0.0f;
    for (int i = threadIdx.x; i < kGrid; i += 256) tv += partials[i];
    #pragma unroll
    for (int s = 32; s > 0; s >>= 1) tv += __shfl_xor(tv, s);
    __shared__ float ws[4];
    if ((threadIdx.x & 63) == 0) ws[threadIdx.x >> 6] = tv;
    __syncthreads();
    if (threadIdx.x == 0) {
        out[0] = (ws[0] + ws[1] + ws[2] + ws[3]) * (1.0f / (float)kUsers);
    }
}

extern "C" void kernel_launch(void* const* d_in, const int* in_sizes, int n_in,
                              void* d_out, int out_size, void* d_ws, size_t ws_size,
                              hipStream_t stream) {
    const float* y_hat  = (const float*)d_in[0];
    const float* y_true = (const float*)d_in[1];
    const float* rnd    = (const float*)d_in[2];
    // d_in[3] = user_idx: contiguous equal-size segments -> never read
    float* partials = (float*)d_ws;          // kGrid floats = 8 KiB scratch
    float* out      = (float*)d_out;

    hipLaunchKernelGGL(prl_user_kernel, dim3(kGrid), dim3(kBlock), 0, stream,
                       y_hat, y_true, rnd, partials);
    hipLaunchKernelGGL(prl_reduce_kernel, dim3(1), dim3(256), 0, stream,
                       partials, out);
}

// Round 7
// 48.883 us; speedup vs baseline: 3.8623x; 1.0267x over previous
//
#include <hip/hip_runtime.h>

// PairwiseRankLoss: U=262144 users x G=64 items, K=2, MARGIN=0.3
// 4 users per 64-lane wave (16 lanes/user, 4 items/lane, float4 loads),
// TWO independent 4-user groups per loop body (R6 lesson: latency-bound;
// dual chains + batched loads raise VALU issue utilization).
// Median: sort both 32-halves ascending (15 bitonic stages; j=1,2 in-lane),
// bitonic split vs mirrored half, a31 = max(lower 32); pos = yt > a31.
// Top-2 rand/side: in-lane (m1,m2) + ror-fold on exact u32 r-bits; locate
// via ballot (lowest flat index on ties = lax.top_k); gather via __shfl.
// Deterministic two-stage reduction via d_ws.

static constexpr int kUsers = 262144;
static constexpr int kBlock = 256;                  // 4 waves / block
static constexpr int kGrid  = 2048;
static constexpr int kWavesPerBlock = kBlock / 64;
static constexpr int kTotalWaves = kGrid * kWavesPerBlock;   // 8192
static constexpr int kUsersPerWave = kUsers / kTotalWaves;   // 32
static constexpr int kUsersPerBody = 8;                      // 2 groups x 4
static constexpr int kBodies = kUsersPerWave / kUsersPerBody; // 4
static constexpr float kMargin = 0.3f;

template<int CTRL>
static __device__ __forceinline__ float dppf(float x) {
    return __uint_as_float((unsigned)__builtin_amdgcn_update_dpp(
        (int)__float_as_uint(x), (int)__float_as_uint(x), CTRL, 0xF, 0xF, false));
}
template<int CTRL>
static __device__ __forceinline__ unsigned dppu(unsigned x) {
    return (unsigned)__builtin_amdgcn_update_dpp((int)x, (int)x, CTRL, 0xF, 0xF, false);
}
template<int PAT>
static __device__ __forceinline__ float swzf(float x) {
    return __uint_as_float((unsigned)__builtin_amdgcn_ds_swizzle(
        (int)__float_as_uint(x), PAT));
}
static __device__ __forceinline__ unsigned umax_(unsigned a, unsigned b){ return a>b?a:b; }
static __device__ __forceinline__ unsigned umin_(unsigned a, unsigned b){ return a<b?a:b; }

#define CE2(a, b, asc) { float mn_=fminf(a,b), mx_=fmaxf(a,b); \
                         (a)=(asc)?mn_:mx_; (b)=(asc)?mx_:mn_; }
#define CE2A(a, b)     { float mn_=fminf(a,b), mx_=fmaxf(a,b); (a)=mn_; (b)=mx_; }
#define CE2D(a, b)     { float mn_=fminf(a,b), mx_=fmaxf(a,b); (a)=mx_; (b)=mn_; }
#define CEX(w, p, km)  { (w) = (km) ? fminf(w,p) : fmaxf(w,p); }

__global__ __launch_bounds__(kBlock, 8)
void prl_user_kernel(const float* __restrict__ y_hat,
                     const float* __restrict__ y_true,
                     const float* __restrict__ rnd,
                     float* __restrict__ partials)
{
    const int lane = threadIdx.x & 63;
    const int wid  = (blockIdx.x * kBlock + threadIdx.x) >> 6;
    const int t    = lane & 15;          // lane within user group
    const int g    = lane >> 4;          // user group (0..3) within wave
    const int tt   = t & 7;              // lane within 32-item sort half

    // loop-invariant keepmin predicates (hoisted to sgpr lane-masks)
    const bool asc4  = (tt & 1) == 0;
    const bool asc8  = (tt & 2) == 0;
    const bool asc16 = (tt & 4) == 0;
    const bool km84  = ((tt & 2) == 0) == ((tt & 1) == 0);
    const bool km168 = ((tt & 4) == 0) == ((tt & 2) == 0);
    const bool km164 = ((tt & 4) == 0) == ((tt & 1) == 0);

    // per-4-user-group pipeline, group-uniform hinge mean as result
    auto process = [&](float4 vh, float4 vt, float4 vr) -> float {
        // ---- sort both 32-halves ascending (local pos q = 4*tt + s) ----
        float w0 = vt.x, w1 = vt.y, w2 = vt.z, w3 = vt.w;
        CE2A(w0, w1); CE2D(w2, w3);
        CE2(w0, w2, asc4); CE2(w1, w3, asc4);
        CE2(w0, w1, asc4); CE2(w2, w3, asc4);
        { float p0=dppf<0xB1>(w0), p1=dppf<0xB1>(w1), p2=dppf<0xB1>(w2), p3=dppf<0xB1>(w3);
          CEX(w0,p0,km84); CEX(w1,p1,km84); CEX(w2,p2,km84); CEX(w3,p3,km84); }
        CE2(w0, w2, asc8); CE2(w1, w3, asc8);
        CE2(w0, w1, asc8); CE2(w2, w3, asc8);
        { float p0=dppf<0x4E>(w0), p1=dppf<0x4E>(w1), p2=dppf<0x4E>(w2), p3=dppf<0x4E>(w3);
          CEX(w0,p0,km168); CEX(w1,p1,km168); CEX(w2,p2,km168); CEX(w3,p3,km168); }
        { float p0=dppf<0xB1>(w0), p1=dppf<0xB1>(w1), p2=dppf<0xB1>(w2), p3=dppf<0xB1>(w3);
          CEX(w0,p0,km164); CEX(w1,p1,km164); CEX(w2,p2,km164); CEX(w3,p3,km164); }
        CE2(w0, w2, asc16); CE2(w1, w3, asc16);
        CE2(w0, w1, asc16); CE2(w2, w3, asc16);
        { float p0=swzf<0x101F>(w0), p1=swzf<0x101F>(w1),
                p2=swzf<0x101F>(w2), p3=swzf<0x101F>(w3);
          CEX(w0,p0,asc16); CEX(w1,p1,asc16); CEX(w2,p2,asc16); CEX(w3,p3,asc16); }
        { float p0=dppf<0x4E>(w0), p1=dppf<0x4E>(w1), p2=dppf<0x4E>(w2), p3=dppf<0x4E>(w3);
          CEX(w0,p0,asc8); CEX(w1,p1,asc8); CEX(w2,p2,asc8); CEX(w3,p3,asc8); }
        { float p0=dppf<0xB1>(w0), p1=dppf<0xB1>(w1), p2=dppf<0xB1>(w2), p3=dppf<0xB1>(w3);
          CEX(w0,p0,asc4); CEX(w1,p1,asc4); CEX(w2,p2,asc4); CEX(w3,p3,asc4); }
        CE2A(w0, w2); CE2A(w1, w3);
        CE2A(w0, w1); CE2A(w2, w3);

        // ---- split vs mirrored other half: lower-32 multiset ----
        const float l0 = fminf(w0, swzf<0x3C1F>(w3));
        const float l1 = fminf(w1, swzf<0x3C1F>(w2));
        const float l2 = fminf(w2, swzf<0x3C1F>(w1));
        const float l3 = fminf(w3, swzf<0x3C1F>(w0));

        // a31 = max of lower 32 (group-uniform after ror fold)
        float m = fmaxf(fmaxf(l0, l1), fmaxf(l2, l3));
        m = fmaxf(m, dppf<0x128>(m));
        m = fmaxf(m, dppf<0x124>(m));
        m = fmaxf(m, dppf<0x122>(m));
        m = fmaxf(m, dppf<0x121>(m));
        const float a31 = m;

        const bool p0m = vt.x > a31, p1m = vt.y > a31,
                   p2m = vt.z > a31, p3m = vt.w > a31;
        const unsigned rb0 = __float_as_uint(vr.x), rb1 = __float_as_uint(vr.y),
                       rb2 = __float_as_uint(vr.z), rb3 = __float_as_uint(vr.w);

        float P0, P1, N0, N1;
        #pragma unroll
        for (int side = 0; side < 2; ++side) {
            const unsigned k0 = ((side == 0) ? p0m : !p0m) ? rb0 : 0u;
            const unsigned k1 = ((side == 0) ? p1m : !p1m) ? rb1 : 0u;
            const unsigned k2 = ((side == 0) ? p2m : !p2m) ? rb2 : 0u;
            const unsigned k3 = ((side == 0) ? p3m : !p3m) ? rb3 : 0u;
            const unsigned a1 = umax_(k0,k1), a2 = umin_(k0,k1);
            const unsigned b1 = umax_(k2,k3), b2 = umin_(k2,k3);
            unsigned m1 = umax_(a1,b1);
            unsigned m2 = umax_(umin_(a1,b1), umax_(a2,b2));
            { unsigned q1=dppu<0x128>(m1), q2=dppu<0x128>(m2);
              unsigned n2=umax_(umin_(m1,q1), umax_(m2,q2)); m1=umax_(m1,q1); m2=n2; }
            { unsigned q1=dppu<0x124>(m1), q2=dppu<0x124>(m2);
              unsigned n2=umax_(umin_(m1,q1), umax_(m2,q2)); m1=umax_(m1,q1); m2=n2; }
            { unsigned q1=dppu<0x122>(m1), q2=dppu<0x122>(m2);
              unsigned n2=umax_(umin_(m1,q1), umax_(m2,q2)); m1=umax_(m1,q1); m2=n2; }
            { unsigned q1=dppu<0x121>(m1), q2=dppu<0x121>(m2);
              unsigned n2=umax_(umin_(m1,q1), umax_(m2,q2)); m1=umax_(m1,q1); m2=n2; }

            float A[2];
            const unsigned vv[2] = { m1, m2 };
            #pragma unroll
            for (int j = 0; j < 2; ++j) {
                const unsigned V = vv[j];
                const bool c0 = (k0 == V), c1 = (k1 == V),
                           c2 = (k2 == V), c3 = (k3 == V);
                const float val = c0 ? vh.x : (c1 ? vh.y : (c2 ? vh.z : vh.w));
                const unsigned long long bal = __ballot(c0 | c1 | c2 | c3);
                const unsigned fld = (unsigned)(bal >> (g << 4)) & 0xFFFFu;
                const int tw = __builtin_ctz(fld);
                A[j] = __shfl(val, (lane & 48) | tw);
            }
            if (side == 0) { P0 = A[0]; P1 = A[1]; }
            else           { N0 = A[0]; N1 = A[1]; }
        }

        float s = 0.0f;
        s += fmaxf(kMargin - (P0 - N0), 0.0f);
        s += fmaxf(kMargin - (P0 - N1), 0.0f);
        s += fmaxf(kMargin - (P1 - N0), 0.0f);
        s += fmaxf(kMargin - (P1 - N1), 0.0f);
        return 0.25f * s;
    };

    float acc = 0.0f;

    #pragma unroll 1
    for (int it = 0; it < kBodies; ++it) {
        const int u0   = wid * kUsersPerWave + it * kUsersPerBody;
        const int idxA = (u0 << 6) + (lane << 2);
        const int idxB = idxA + 256;
        // batch all 6 loads up front: B's latency hides under A's compute
        const float4 vtA = *reinterpret_cast<const float4*>(y_true + idxA);
        const float4 vtB = *reinterpret_cast<const float4*>(y_true + idxB);
        const float4 vrA = *reinterpret_cast<const float4*>(rnd   + idxA);
        const float4 vrB = *reinterpret_cast<const float4*>(rnd   + idxB);
        const float4 vhA = *reinterpret_cast<const float4*>(y_hat + idxA);
        const float4 vhB = *reinterpret_cast<const float4*>(y_hat + idxB);

        acc += process(vhA, vtA, vrA);
        acc += process(vhB, vtB, vrB);
    }

    // acc is uniform within each 16-lane group; sum the 4 group leaders
    float contrib = (t == 0) ? acc : 0.0f;
    contrib += __shfl_xor(contrib, 32);
    contrib += __shfl_xor(contrib, 16);

    __shared__ float wsum[kWavesPerBlock];
    if (lane == 0) wsum[threadIdx.x >> 6] = contrib;
    __syncthreads();
    if (threadIdx.x == 0) {
        float tsum = 0.0f;
        #pragma unroll
        for (int i = 0; i < kWavesPerBlock; ++i) tsum += wsum[i];
        partials[blockIdx.x] = tsum;
    }
}

__global__ void prl_reduce_kernel(const float* __restrict__ partials,
                                  float* __restrict__ out)
{
    float tv = 0.0f;
    for (int i = threadIdx.x; i < kGrid; i += 256) tv += partials[i];
    #pragma unroll
    for (int s = 32; s > 0; s >>= 1) tv += __shfl_xor(tv, s);
    __shared__ float ws[4];
    if ((threadIdx.x & 63) == 0) ws[threadIdx.x >> 6] = tv;
    __syncthreads();
    if (threadIdx.x == 0) {
        out[0] = (ws[0] + ws[1] + ws[2] + ws[3]) * (1.0f / (float)kUsers);
    }
}

extern "C" void kernel_launch(void* const* d_in, const int* in_sizes, int n_in,
                              void* d_out, int out_size, void* d_ws, size_t ws_size,
                              hipStream_t stream) {
    const float* y_hat  = (const float*)d_in[0];
    const float* y_true = (const float*)d_in[1];
    const float* rnd    = (const float*)d_in[2];
    // d_in[3] = user_idx: contiguous equal-size segments -> never read
    float* partials = (float*)d_ws;          // kGrid floats = 8 KiB scratch
    float* out      = (float*)d_out;

    hipLaunchKernelGGL(prl_user_kernel, dim3(kGrid), dim3(kBlock), 0, stream,
                       y_hat, y_true, rnd, partials);
    hipLaunchKernelGGL(prl_reduce_kernel, dim3(1), dim3(256), 0, stream,
                       partials, out);
}